// Round 13
// baseline (191.764 us; speedup 1.0000x reference)
//
#include <hip/hip_runtime.h>
#include <hip/hip_bf16.h>

typedef __attribute__((ext_vector_type(8)))  short short8;
typedef __attribute__((ext_vector_type(16))) float f32x16;

#define NVEC 65536   // B*H*W
#define KC   1024
#define DD   64
#define KSPLIT 4     // k-ranges (blockIdx.y), 256 codes each

// d_out layout (f32): [0]=loss, [1..4194305)=z_q, [4194305]=ppl, [4194306..)=idx
#define OUT_ZQ   1
#define OUT_PPL  4194305
#define OUT_IDX  4194306

// out-region scratch (f32 offsets from out+OUT_ZQ): read only by pre-zq kernels
#define SC_SZ    0         // f32[65536]
#define SC_SN    65536     // f32[65536]
#define SC_FBL   131072    // u32[65536]
#define SC_RD1   196608    // f32[4][65536]
#define SC_RK1   458752    // u32[4][65536]
#define SC_RD2   720896    // f32[4][65536]   (end 983040 < 4194304)

// ws layout (bytes)
#define WS_FILT  0         // u16[65536] = 131072 (read by zq_kernel)
#define WS_HIST  131072    // int[1024]  = 4096
#define WS_SUMSQ 135168    // double     = 8
#define WS_FBCNT 135176    // u32 (+4 pad)
#define WS_SE    135184    // f32[1024]  = 4096
#define WS_EBFH  139280    // bf16[1024][64] shuffled (hi) = 131072
#define WS_EBFL  270352    // bf16[1024][64] shuffled (lo) = 131072
#define WS_EMBT  401424    // f32[64][1024] = 262144

// ---------------------------------------------------------------------------
// prep_z: sz[n] = np.sum(zf**2) in numpy pairwise order (verified bit-exact);
// snv[n] = sum|z| for the error margin.
__global__ __launch_bounds__(256) void prep_z(const float* __restrict__ z,
                                              float* __restrict__ sz,
                                              float* __restrict__ snv) {
    const int n  = blockIdx.x * 256 + threadIdx.x;
    const int b  = n >> 10;
    const int hw = n & 1023;
    const float* zp = z + (size_t)b * 65536 + hw;
    float r[8];
    float sa = 0.0f;
    #pragma unroll
    for (int c = 0; c < 64; ++c) {
        float v = zp[(size_t)c * 1024];
        float s = __fmul_rn(v, v);
        if (c < 8) r[c] = s;
        else       r[c & 7] = __fadd_rn(r[c & 7], s);
        sa += fabsf(v);
    }
    sz[n] = __fadd_rn(__fadd_rn(__fadd_rn(r[0], r[1]), __fadd_rn(r[2], r[3])),
                      __fadd_rn(__fadd_rn(r[4], r[5]), __fadd_rn(r[6], r[7])));
    snv[n] = sa;
}

// prep_emb: se[k] (verified pairwise), split-bf16 shuffled rows (hi+lo), and
// embT[c][k] f32 transpose for the exact fallback.  (verified R12)
__global__ __launch_bounds__(256) void prep_emb(const float* __restrict__ emb,
                                                float* __restrict__ se,
                                                unsigned short* __restrict__ ebfh,
                                                unsigned short* __restrict__ ebfl,
                                                float* __restrict__ embT) {
    __shared__ float tile[64][65];
    const int tid = threadIdx.x;
    const int k0  = blockIdx.x * 64;
    {
        const int r = tid >> 2, q = tid & 3;
        const float* row = emb + (size_t)(k0 + r) * 64 + q * 16;
        #pragma unroll
        for (int i = 0; i < 4; ++i) {
            float4 v = *(const float4*)(row + i * 4);
            tile[r][q * 16 + i * 4 + 0] = v.x;
            tile[r][q * 16 + i * 4 + 1] = v.y;
            tile[r][q * 16 + i * 4 + 2] = v.z;
            tile[r][q * 16 + i * 4 + 3] = v.w;
        }
    }
    __syncthreads();
    if (tid < 64) {
        float r[8];
        #pragma unroll
        for (int c = 0; c < 64; ++c) {
            float v = tile[tid][c];
            float s = __fmul_rn(v, v);
            if (c < 8) r[c] = s;
            else       r[c & 7] = __fadd_rn(r[c & 7], s);
        }
        se[k0 + tid] = __fadd_rn(
            __fadd_rn(__fadd_rn(r[0], r[1]), __fadd_rn(r[2], r[3])),
            __fadd_rn(__fadd_rn(r[4], r[5]), __fadd_rn(r[6], r[7])));
    }
    const int kl = tid & 63, cg = tid >> 6;
    #pragma unroll
    for (int i = 0; i < 16; ++i) {
        int c = cg * 16 + i;
        embT[(size_t)c * KC + k0 + kl] = tile[kl][c];
    }
    unsigned* ebh32 = (unsigned*)ebfh;
    unsigned* ebl32 = (unsigned*)ebfl;
    #pragma unroll
    for (int pp = 0; pp < 8; ++pp) {
        int p  = cg * 16 + pp * 2;
        int s  = p >> 4, rem = p & 15;
        int q  = rem >> 3, h = (rem >> 2) & 1, j = rem & 3;
        int c0 = s * 16 + 8 * h + 4 * q + j;
        float v0 = tile[kl][c0], v1 = tile[kl][c0 + 1];
        __hip_bfloat16 h0 = __float2bfloat16(v0);
        __hip_bfloat16 h1 = __float2bfloat16(v1);
        float r0 = v0 - __bfloat162float(h0);
        float r1 = v1 - __bfloat162float(h1);
        __hip_bfloat16 l0 = __float2bfloat16(r0);
        __hip_bfloat16 l1 = __float2bfloat16(r1);
        unsigned uh0 = *(unsigned short*)&h0, uh1 = *(unsigned short*)&h1;
        unsigned ul0 = *(unsigned short*)&l0, ul1 = *(unsigned short*)&l1;
        size_t widx = ((size_t)(k0 + kl) * 64 + p) >> 1;
        ebh32[widx] = uh0 | (uh1 << 16);
        ebl32[widx] = ul0 | (ul1 << 16);
    }
}

// ---------------------------------------------------------------------------
// phase1: split-bf16 MFMA filter, k-split x4, LDS-free.
// Per tile: 3 INDEPENDENT acc chains (hh, lh, hl) of depth 4 each; epilogue
// g = fmaf(-2,aC, fmaf(-2,aB, fmaf(-2,aA, se))) -- extra rounding ~1e-8,
// buried under the R12-validated margin. Per (lane,row) top1(d,k)+top2(d);
// per-n finalize = 5-step shfl_xor reduce within 32-lane halves; per-range
// (d1,k1,d2) stored to scratch for the merge kernel.
__global__ __launch_bounds__(256)
void phase1(const float* __restrict__ z,
            const unsigned short* __restrict__ ebfh,
            const unsigned short* __restrict__ ebfl,
            const float* __restrict__ se,
            float* __restrict__ rd1,
            unsigned* __restrict__ rk1,
            float* __restrict__ rd2) {
    const int tid = threadIdx.x;
    const int w   = tid >> 6;
    const int l   = tid & 63;
    const int q   = l >> 5;
    const int col = l & 31;
    const int nwave = blockIdx.x * 128 + w * 32;
    const int kbase = blockIdx.y * (KC / KSPLIT);

    // A-frags: z split into hi+lo bf16. af*[s] elem (4h+j) <-> c = s*16+8h+4q+j
    const int nA = nwave + col;
    const int bA = nA >> 10, hwA = nA & 1023;
    short8 afh[4], afl[4];
    #pragma unroll
    for (int s = 0; s < 4; ++s)
        #pragma unroll
        for (int h = 0; h < 2; ++h)
            #pragma unroll
            for (int j = 0; j < 4; ++j) {
                int c = s * 16 + 8 * h + 4 * q + j;
                float v = z[(size_t)bA * 65536 + (size_t)c * 1024 + hwA];
                __hip_bfloat16 bh = __float2bfloat16(v);
                float rv = v - __bfloat162float(bh);
                __hip_bfloat16 bl = __float2bfloat16(rv);
                afh[s][4 * h + j] = *(short*)&bh;
                afl[s][4 * h + j] = *(short*)&bl;
            }

    float K1d[16], K2d[16]; unsigned K1k[16];
    #pragma unroll
    for (int r = 0; r < 16; ++r) { K1d[r] = K2d[r] = __builtin_inff(); K1k[r] = 0; }

    for (int t = 0; t < (KC / KSPLIT) / 32; ++t) {
        const int kcur = kbase + t * 32 + col;
        const unsigned short* ebh = ebfh + (size_t)kcur * 64 + q * 8;
        const unsigned short* ebl = ebfl + (size_t)kcur * 64 + q * 8;
        short8 bh0 = *(const short8*)(ebh + 0);
        short8 bh1 = *(const short8*)(ebh + 16);
        short8 bh2 = *(const short8*)(ebh + 32);
        short8 bh3 = *(const short8*)(ebh + 48);
        short8 bl0 = *(const short8*)(ebl + 0);
        short8 bl1 = *(const short8*)(ebl + 16);
        short8 bl2 = *(const short8*)(ebl + 32);
        short8 bl3 = *(const short8*)(ebl + 48);
        const float sek = se[kcur];
        f32x16 aA, aB, aC;
        #pragma unroll
        for (int r = 0; r < 16; ++r) { aA[r] = 0.0f; aB[r] = 0.0f; aC[r] = 0.0f; }
        // three independent chains, depth 4 each
        aA = __builtin_amdgcn_mfma_f32_32x32x16_bf16(afh[0], bh0, aA, 0, 0, 0);
        aB = __builtin_amdgcn_mfma_f32_32x32x16_bf16(afl[0], bh0, aB, 0, 0, 0);
        aC = __builtin_amdgcn_mfma_f32_32x32x16_bf16(afh[0], bl0, aC, 0, 0, 0);
        aA = __builtin_amdgcn_mfma_f32_32x32x16_bf16(afh[1], bh1, aA, 0, 0, 0);
        aB = __builtin_amdgcn_mfma_f32_32x32x16_bf16(afl[1], bh1, aB, 0, 0, 0);
        aC = __builtin_amdgcn_mfma_f32_32x32x16_bf16(afh[1], bl1, aC, 0, 0, 0);
        aA = __builtin_amdgcn_mfma_f32_32x32x16_bf16(afh[2], bh2, aA, 0, 0, 0);
        aB = __builtin_amdgcn_mfma_f32_32x32x16_bf16(afl[2], bh2, aB, 0, 0, 0);
        aC = __builtin_amdgcn_mfma_f32_32x32x16_bf16(afh[2], bl2, aC, 0, 0, 0);
        aA = __builtin_amdgcn_mfma_f32_32x32x16_bf16(afh[3], bh3, aA, 0, 0, 0);
        aB = __builtin_amdgcn_mfma_f32_32x32x16_bf16(afl[3], bh3, aB, 0, 0, 0);
        aC = __builtin_amdgcn_mfma_f32_32x32x16_bf16(afh[3], bl3, aC, 0, 0, 0);
        #pragma unroll
        for (int r = 0; r < 16; ++r) {
            float d = __fmaf_rn(-2.0f, aC[r],
                      __fmaf_rn(-2.0f, aB[r],
                      __fmaf_rn(-2.0f, aA[r], sek)));
            bool c1 = d < K1d[r];
            bool c2 = d < K2d[r];
            K2d[r] = c1 ? K1d[r] : (c2 ? d : K2d[r]);
            K1k[r] = c1 ? (unsigned)kcur : K1k[r];
            K1d[r] = c1 ? d : K1d[r];
        }
    }

    // per-n finalize: reduce over the 32 lanes of each half (cols of one row)
    const size_t roff = (size_t)blockIdx.y * NVEC;
    #pragma unroll
    for (int r = 0; r < 16; ++r) {
        float    d1 = K1d[r];
        unsigned k1 = K1k[r];
        float    d2 = K2d[r];
        #pragma unroll
        for (int off = 1; off < 32; off <<= 1) {
            float    od1 = __shfl_xor(d1, off, 64);
            unsigned ok1 = (unsigned)__shfl_xor((int)k1, off, 64);
            float    od2 = __shfl_xor(d2, off, 64);
            bool better = (od1 < d1) || (od1 == d1 && ok1 < k1);
            float loser = better ? d1 : od1;
            d2 = fminf(fminf(d2, od2), loser);
            d1 = better ? od1 : d1;
            k1 = better ? ok1 : k1;
        }
        if ((l & 31) == 0) {
            int row = (r & 3) + 8 * (r >> 2) + 4 * q;
            int n   = nwave + row;
            rd1[roff + n] = d1;
            rk1[roff + n] = k1;
            rd2[roff + n] = d2;
        }
    }
}

// ---------------------------------------------------------------------------
// merge: combine KSPLIT per-range results per n; margin test; emit filt/fblist.
__global__ __launch_bounds__(256)
void merge_kernel(const float* __restrict__ rd1,
                  const unsigned* __restrict__ rk1,
                  const float* __restrict__ rd2,
                  const float* __restrict__ snv,
                  unsigned short* __restrict__ filt,
                  unsigned* __restrict__ fbcnt,
                  unsigned* __restrict__ fblist) {
    const int n = blockIdx.x * 256 + threadIdx.x;
    float bd = __builtin_inff(); unsigned bk = 0; int br = 0;
    #pragma unroll
    for (int r = 0; r < KSPLIT; ++r) {
        float    d = rd1[(size_t)r * NVEC + n];
        unsigned k = rk1[(size_t)r * NVEC + n];
        bool better = (d < bd) || (d == bd && k < bk);
        if (better) { bd = d; bk = k; br = r; }
    }
    float b2 = __builtin_inff();
    #pragma unroll
    for (int r = 0; r < KSPLIT; ++r) {
        b2 = fminf(b2, rd2[(size_t)r * NVEC + n]);
        if (r != br) b2 = fminf(b2, rd1[(size_t)r * NVEC + n]);
    }
    float margin = __fmaf_rn(snv[n], 2.0e-7f, 6.0e-5f);
    filt[n] = (unsigned short)bk;
    if (b2 <= bd + margin) {
        unsigned pos = atomicAdd(fbcnt, 1u);
        fblist[pos] = (unsigned)n;
    }
}

// ---------------------------------------------------------------------------
// fallback: wave per flagged n; exact f32 scan of all 1024 codes (verified).
__global__ __launch_bounds__(256)
void fallback_kernel(const float* __restrict__ z,
                     const float* __restrict__ embT,
                     const float* __restrict__ se,
                     const float* __restrict__ sz,
                     const unsigned int* __restrict__ fbcnt,
                     const unsigned int* __restrict__ fblist,
                     unsigned short* __restrict__ filt) {
    const int tid = threadIdx.x;
    const int w = tid >> 6, l = tid & 63;
    const unsigned total = *fbcnt;
    for (unsigned i = blockIdx.x * 4 + w; i < total; i += gridDim.x * 4) {
        const int n = (int)fblist[i];
        const int b = n >> 10, hw = n & 1023;
        float zl = z[(size_t)b * 65536 + (size_t)l * 1024 + hw];  // lane l = c
        float acc[16];
        #pragma unroll
        for (int p = 0; p < 16; ++p) acc[p] = 0.0f;
        for (int c = 0; c < 64; ++c) {
            float zc = __shfl(zl, c, 64);
            const float* eb = embT + (size_t)c * KC + l;
            #pragma unroll
            for (int p = 0; p < 16; ++p)
                acc[p] = __fmaf_rn(zc, eb[p * 64], acc[p]);
        }
        const float szn = sz[n];
        unsigned long long best = 0xFFFFFFFFFFFFFFFFULL;
        #pragma unroll
        for (int p = 0; p < 16; ++p) {
            int kp = l + p * 64;
            float d = __fmaf_rn(-2.0f, acc[p], __fadd_rn(szn, se[kp]));
            unsigned m = __float_as_uint(d);
            m ^= ((int)m < 0) ? 0xFFFFFFFFu : 0x80000000u;
            unsigned long long key =
                ((unsigned long long)m << 10) | (unsigned)kp;
            best = key < best ? key : best;
        }
        #pragma unroll
        for (int off = 32; off; off >>= 1) {
            unsigned long long o = __shfl_xor(best, off, 64);
            best = o < best ? o : best;
        }
        if (l == 0) filt[n] = (unsigned short)(best & 1023ULL);
    }
}

// ---------------------------------------------------------------------------
// zq_kernel: idx out, hist, straight-through z_q, sumsq.  (verified)
__global__ __launch_bounds__(256) void zq_kernel(const float* __restrict__ z,
                                                 const float* __restrict__ emb,
                                                 const unsigned short* __restrict__ filt,
                                                 float* __restrict__ out,
                                                 int* __restrict__ hist,
                                                 double* __restrict__ sumsq) {
    __shared__ double red[256];
    const int tid = threadIdx.x;
    const int n   = blockIdx.x * 256 + tid;
    const int b   = n >> 10;
    const int hw  = n & 1023;
    const int idx = (int)filt[n] & 1023;

    out[OUT_IDX + n] = (float)idx;
    atomicAdd(&hist[idx], 1);

    const float* zp = z   + (size_t)b * 65536 + hw;
    float*       op = out + OUT_ZQ + (size_t)b * 65536 + hw;
    const float* er = emb + (size_t)idx * DD;
    double s = 0.0;
    #pragma unroll
    for (int c = 0; c < DD; ++c) {
        float zv   = zp[(size_t)c * 1024];
        float ev   = er[c];
        float diff = ev - zv;                  // z_q - z
        op[(size_t)c * 1024] = zv + diff;      // straight-through
        s = fma((double)diff, (double)diff, s);
    }
    red[tid] = s;
    __syncthreads();
    for (int off = 128; off > 0; off >>= 1) {
        if (tid < off) red[tid] += red[tid + off];
        __syncthreads();
    }
    if (tid == 0) atomicAdd(sumsq, red[0]);
}

__global__ __launch_bounds__(256) void final_kernel(const int* __restrict__ hist,
                                                    const double* __restrict__ sumsq,
                                                    float* __restrict__ out) {
    __shared__ double red[256];
    const int tid = threadIdx.x;
    double s = 0.0;
    #pragma unroll
    for (int j = 0; j < 4; ++j) {
        int   kk = j * 256 + tid;
        float em = (float)hist[kk] * (1.0f / 65536.0f);
        float t  = em * logf(em + 1e-10f);
        s += (double)t;
    }
    red[tid] = s;
    __syncthreads();
    for (int off = 128; off > 0; off >>= 1) {
        if (tid < off) red[tid] += red[tid + off];
        __syncthreads();
    }
    if (tid == 0) {
        out[OUT_PPL] = expf(-(float)red[0]);
        out[0]       = 1.25f * (float)(sumsq[0] / 4194304.0);
    }
}

extern "C" void kernel_launch(void* const* d_in, const int* in_sizes, int n_in,
                              void* d_out, int out_size, void* d_ws, size_t ws_size,
                              hipStream_t stream) {
    const float* z   = (const float*)d_in[0];
    const float* emb = (const float*)d_in[1];
    float* out = (float*)d_out;
    char*  ws  = (char*)d_ws;

    unsigned short* filt  = (unsigned short*)(ws + WS_FILT);
    int*            hist  = (int*)(ws + WS_HIST);
    double*         sumsq = (double*)(ws + WS_SUMSQ);
    unsigned*       fbcnt = (unsigned*)(ws + WS_FBCNT);
    float*          se    = (float*)(ws + WS_SE);
    unsigned short* ebfh  = (unsigned short*)(ws + WS_EBFH);
    unsigned short* ebfl  = (unsigned short*)(ws + WS_EBFL);
    float*          embT  = (float*)(ws + WS_EMBT);

    float*    zscr   = out + OUT_ZQ;
    float*    sz     = zscr + SC_SZ;
    float*    snv    = zscr + SC_SN;
    unsigned* fblist = (unsigned*)(zscr + SC_FBL);
    float*    rd1    = zscr + SC_RD1;
    unsigned* rk1    = (unsigned*)(zscr + SC_RK1);
    float*    rd2    = zscr + SC_RD2;

    hipMemsetAsync(ws + WS_HIST, 0, 4112, stream);  // hist + sumsq + fbcnt

    prep_z  <<<NVEC / 256, 256, 0, stream>>>(z, sz, snv);
    prep_emb<<<KC / 64,    256, 0, stream>>>(emb, se, ebfh, ebfl, embT);
    phase1  <<<dim3(NVEC / 128, KSPLIT), 256, 0, stream>>>(z, ebfh, ebfl, se,
                                                           rd1, rk1, rd2);
    merge_kernel<<<NVEC / 256, 256, 0, stream>>>(rd1, rk1, rd2, snv,
                                                 filt, fbcnt, fblist);
    fallback_kernel<<<128, 256, 0, stream>>>(z, embT, se, sz, fbcnt, fblist, filt);
    zq_kernel      <<<NVEC / 256, 256, 0, stream>>>(z, emb, filt, out, hist, sumsq);
    final_kernel   <<<1, 256, 0, stream>>>(hist, sumsq, out);
}